// Round 6
// baseline (215.913 us; speedup 1.0000x reference)
//
#include <hip/hip_runtime.h>
#include <hip/hip_bf16.h>

#define B_ 8
#define N_ 4096
#define M_ 4096
#define D_ 64
#define BNT (B_ * N_)   // 32768
#define BMT (B_ * M_)   // 32768
#define TA 128          // A band rows per block (fragments in registers)
#define TB 128          // B tile rows (LDS, double-buffered)
#define CHUNK_TILES 8   // B tiles per block
#define CHUNK_B (TB * CHUNK_TILES)        // 1024
#define MCHUNK (M_ / CHUNK_B)             // 4

typedef short bf16x8 __attribute__((ext_vector_type(8)));
typedef float f32x4 __attribute__((ext_vector_type(4)));

__device__ __forceinline__ unsigned short f2bf(float f) {
  __hip_bfloat16 h = __float2bfloat16(f);
  return *reinterpret_cast<unsigned short*>(&h);
}

// Order-preserving float -> uint key for atomicMin/atomicMax(unsigned).
__device__ __forceinline__ unsigned fkey(float f) {
  unsigned b = __float_as_uint(f);
  return b ^ ((unsigned)((int)b >> 31) | 0x80000000u);
}
__device__ __forceinline__ float funkey(unsigned k) {
  unsigned b = (k & 0x80000000u) ? (k ^ 0x80000000u) : ~k;
  return __uint_as_float(b);
}

__device__ __forceinline__ bf16x8 cvt8(float4 lo, float4 hi) {
  union { unsigned short u[8]; bf16x8 v; } r;
  r.u[0] = f2bf(lo.x); r.u[1] = f2bf(lo.y); r.u[2] = f2bf(lo.z); r.u[3] = f2bf(lo.w);
  r.u[4] = f2bf(hi.x); r.u[5] = f2bf(hi.y); r.u[6] = f2bf(hi.z); r.u[7] = f2bf(hi.w);
  return r.v;
}

__device__ __forceinline__ void gload_lds16(const void* g, void* l) {
  __builtin_amdgcn_global_load_lds(
      (const __attribute__((address_space(1))) unsigned int*)g,
      (__attribute__((address_space(3))) unsigned int*)l, 16, 0, 0);
}

// Stage a ROWSx64 bf16 tile into XOR-swizzled LDS (row pitch 128B,
// swizzle byte ^= (row&7)<<4). BF: direct global->LDS DMA with pre-swizzled
// per-lane source (m173). !BF: fp32 load + convert + swizzled ds_write.
template <int ROWS, bool BF>
__device__ __forceinline__ void stage_tile(const void* gsrc, unsigned short* lds,
                                           int t, int srcpat) {
  if (BF) {
    constexpr int PER_WAVE = (ROWS * 128 / 1024) / 4;
    const char* gp = (const char*)gsrc;
    int w = t >> 6;
#pragma unroll
    for (int i = 0; i < PER_WAVE; i++) {
      int q = w * PER_WAVE + i;
      gload_lds16(gp + q * 1024 + srcpat, (char*)lds + q * 1024);
    }
  } else {
    const float4* g4 = (const float4*)gsrc;
#pragma unroll
    for (int i = 0; i < ROWS * 16 / 256; i++) {
      int off = i * 256 + t;
      float4 v = g4[off];
      int row = off >> 4;
      int cb = (off & 15) * 8;
      int ba = (row * 128 + cb) ^ ((row & 7) << 4);
      ushort4 p;
      p.x = f2bf(v.x); p.y = f2bf(v.y); p.z = f2bf(v.z); p.w = f2bf(v.w);
      *(ushort4*)((char*)lds + ba) = p;
    }
  }
}

// Kernel 1: norms + min-array + gmax init (+ optional conversion).
// predbf gets -2*pred folded in (exact power-of-2 scale, no extra rounding):
// the fused gram then directly produces y2 - 2<a,b> via MFMA C-injection.
template <bool CONV>
__global__ __launch_bounds__(256) void prep_kernel(
    const float* __restrict__ pred, const float* __restrict__ label,
    unsigned short* __restrict__ predbf, unsigned short* __restrict__ labelbf,
    float* __restrict__ x2, float* __restrict__ y2,
    unsigned* __restrict__ minN, unsigned* __restrict__ minM,
    unsigned* __restrict__ gmax) {
  int t = threadIdx.x;
  int lane = t & 15;
  long row = (long)blockIdx.x * 16 + (t >> 4);
  bool isA = row < BNT;
  const float4* src;
  unsigned short* bdst;
  float* ndst;
  unsigned* mdst;
  if (isA) {
    src = (const float4*)(pred + row * D_);
    bdst = predbf + row * D_;
    ndst = x2 + row;
    mdst = minN + row;
  } else {
    long r2 = row - BNT;
    src = (const float4*)(label + r2 * D_);
    bdst = labelbf + r2 * D_;
    ndst = y2 + r2;
    mdst = minM + r2;
  }
  float4 v = src[lane];
  if (CONV) {
    float s = isA ? -2.f : 1.f;
    ushort4 p;
    p.x = f2bf(s * v.x); p.y = f2bf(s * v.y);
    p.z = f2bf(s * v.z); p.w = f2bf(s * v.w);
    *(ushort4*)(bdst + lane * 4) = p;
  }
  float s = v.x * v.x + v.y * v.y + v.z * v.z + v.w * v.w;
  s += __shfl_xor(s, 1);
  s += __shfl_xor(s, 2);
  s += __shfl_xor(s, 4);
  s += __shfl_xor(s, 8);
  if (lane == 0) {
    *ndst = s;
    *mdst = 0xFFFFFFFFu;  // +inf key
  }
  if (blockIdx.x == 0 && t < 2) gmax[t] = 0u;
}

// Kernel 2: fused big-tile pass. Block = 4 waves (2x2), A-band 128 rows in
// registers (wave row-half), B staged in double-buffered 128-row LDS tiles.
// Per iter: 128x128 output tile, 32 MFMA/wave. acc initialized to splat(y2[m])
// and A pre-scaled by -2  =>  acc = y2[m] - 2<a,b> straight out of MFMA.
//   minN[n]: rmin regs across chunk -> shfl + cross-wave LDS -> atomic (end)
//   minM[m]: per-iter add x2 + min-tree + 2 shfl -> cmSlab; batch flush (end)
template <bool BF>
__global__ __launch_bounds__(256, 3) void fused_kernel(
    const void* __restrict__ Asrc, const void* __restrict__ Bsrc,
    const float* __restrict__ x2g, const float* __restrict__ y2g,
    unsigned* __restrict__ minN, unsigned* __restrict__ minM) {
  __shared__ alignas(16) unsigned short Bs[2][TB * 64];
  __shared__ float y2l[CHUNK_B];
  __shared__ float cmSlab[2][CHUNK_B];
  __shared__ float red[2][TA];

  const int t = threadIdx.x;
  const int b = blockIdx.z;
  const int a0 = blockIdx.x * TA;
  const int m0 = blockIdx.y * CHUNK_B;
  const int w = t >> 6, l = t & 63;
  const int g = l >> 4, c = l & 15;
  const int wr = w >> 1, wc = w & 1;
  const int srcpat = (l >> 3) * 128 + (((l & 7) * 16) ^ ((l >> 3) << 4));

  const size_t rowbytes = BF ? 128 : 256;
  const char* Bgl = (const char*)Bsrc + ((size_t)b * M_ + m0) * rowbytes;

  // y2 chunk -> LDS (4KB, once)
  ((float4*)y2l)[t] = ((const float4*)(y2g + (size_t)b * M_ + m0))[t];

  // stage first B tile
  stage_tile<TB, BF>(Bgl, Bs[0], t, srcpat);

  // A fragments (this wave's 64-row half), direct global->reg
  bf16x8 af[2][4];
  if (BF) {
    const unsigned short* Ab =
        (const unsigned short*)Asrc + ((size_t)b * N_ + a0) * D_;
#pragma unroll
    for (int kk = 0; kk < 2; kk++)
#pragma unroll
      for (int mi = 0; mi < 4; mi++)
        af[kk][mi] =
            *(const bf16x8*)(Ab + (size_t)(wr * 64 + mi * 16 + c) * D_ + kk * 32 + g * 8);
  } else {
    const float* Af = (const float*)Asrc + ((size_t)b * N_ + a0) * D_;
#pragma unroll
    for (int kk = 0; kk < 2; kk++)
#pragma unroll
      for (int mi = 0; mi < 4; mi++) {
        const float4* p =
            (const float4*)(Af + (size_t)(wr * 64 + mi * 16 + c) * D_ + kk * 32 + g * 8);
        float4 lo = p[0], hi = p[1];
        lo.x *= -2.f; lo.y *= -2.f; lo.z *= -2.f; lo.w *= -2.f;
        hi.x *= -2.f; hi.y *= -2.f; hi.z *= -2.f; hi.w *= -2.f;
        af[kk][mi] = cvt8(lo, hi);
      }
  }

  // x2 per output A-row (loop-invariant)
  float x2v[4][4];
#pragma unroll
  for (int mi = 0; mi < 4; mi++)
#pragma unroll
    for (int e = 0; e < 4; e++)
      x2v[mi][e] = x2g[(size_t)b * N_ + a0 + wr * 64 + mi * 16 + g * 4 + e];

  float rmin[4][4];
#pragma unroll
  for (int mi = 0; mi < 4; mi++)
#pragma unroll
    for (int e = 0; e < 4; e++) rmin[mi][e] = INFINITY;

  __syncthreads();  // first tile + y2l ready

#pragma unroll
  for (int it = 0; it < CHUNK_TILES; it++) {
    if (it + 1 < CHUNK_TILES)
      stage_tile<TB, BF>(Bgl + (size_t)(it + 1) * TB * rowbytes,
                         Bs[(it + 1) & 1], t, srcpat);
    const char* Bcur = (const char*)Bs[it & 1];

    float nbv[4];
#pragma unroll
    for (int ni = 0; ni < 4; ni++)
      nbv[ni] = y2l[it * TB + wc * 64 + ni * 16 + c];

#pragma unroll
    for (int h = 0; h < 2; h++) {
      // B fragments for 2 ni columns (this wave's wc half)
      bf16x8 b0[2], b1[2];
#pragma unroll
      for (int nj = 0; nj < 2; nj++) {
        int r = wc * 64 + (h * 2 + nj) * 16 + c;
        b0[nj] = *(const bf16x8*)(Bcur + ((r * 128 + g * 16) ^ ((r & 7) << 4)));
        b1[nj] = *(const bf16x8*)(Bcur + ((r * 128 + 64 + g * 16) ^ ((r & 7) << 4)));
      }
      // acc init = splat(y2[m]); A carries -2 => acc = y2 - 2<a,b>
      f32x4 acc[4][2];
#pragma unroll
      for (int mi = 0; mi < 4; mi++)
#pragma unroll
        for (int nj = 0; nj < 2; nj++) {
          float nv = nbv[h * 2 + nj];
          acc[mi][nj] = (f32x4){nv, nv, nv, nv};
        }
#pragma unroll
      for (int mi = 0; mi < 4; mi++)
#pragma unroll
        for (int nj = 0; nj < 2; nj++)
          acc[mi][nj] = __builtin_amdgcn_mfma_f32_16x16x32_bf16(
              af[0][mi], b0[nj], acc[mi][nj], 0, 0, 0);
#pragma unroll
      for (int mi = 0; mi < 4; mi++)
#pragma unroll
        for (int nj = 0; nj < 2; nj++)
          acc[mi][nj] = __builtin_amdgcn_mfma_f32_16x16x32_bf16(
              af[1][mi], b1[nj], acc[mi][nj], 0, 0, 0);

      // epilogue: rmin = fmin(rmin, acc); cmin = min(acc + x2) - y2
#pragma unroll
      for (int nj = 0; nj < 2; nj++) {
        float cm = INFINITY;
#pragma unroll
        for (int mi = 0; mi < 4; mi++)
#pragma unroll
          for (int e = 0; e < 4; e++) {
            float v = acc[mi][nj][e];
            rmin[mi][e] = fminf(rmin[mi][e], v);
            cm = fminf(cm, v + x2v[mi][e]);
          }
        cm = fminf(cm, __shfl_xor(cm, 16));
        cm = fminf(cm, __shfl_xor(cm, 32));
        if (g == 0)
          cmSlab[wr][it * TB + wc * 64 + (h * 2 + nj) * 16 + c] =
              cm - nbv[h * 2 + nj];
      }
    }
    __syncthreads();
  }

  // rmin finish: c-lane shfl reduce, cross-wc LDS combine, one atomic per row
#pragma unroll
  for (int mi = 0; mi < 4; mi++)
#pragma unroll
    for (int e = 0; e < 4; e++) {
      float r = rmin[mi][e];
      r = fminf(r, __shfl_xor(r, 1));
      r = fminf(r, __shfl_xor(r, 2));
      r = fminf(r, __shfl_xor(r, 4));
      r = fminf(r, __shfl_xor(r, 8));
      rmin[mi][e] = r;
    }
  if (c == 0) {
#pragma unroll
    for (int mi = 0; mi < 4; mi++)
#pragma unroll
      for (int e = 0; e < 4; e++)
        red[wc][wr * 64 + mi * 16 + g * 4 + e] = rmin[mi][e];
  }
  __syncthreads();
  if (t < TA) {
    float m = fminf(red[0][t], red[1][t]);
    atomicMin(&minN[(size_t)b * N_ + a0 + t], fkey(m));
  }
  // col-min flush: combine wr slabs, one atomic per B row of the chunk
#pragma unroll
  for (int i = 0; i < CHUNK_B / 256; i++) {
    int r = i * 256 + t;
    float v = fminf(cmSlab[0][r], cmSlab[1][r]);
    atomicMin(&minM[(size_t)b * M_ + m0 + r], fkey(v));
  }
}

// Kernel 3a: per-slice max of (norm + min), atomicMax into gmax[dir].
__global__ __launch_bounds__(256) void final1_kernel(
    const unsigned* __restrict__ minN, const unsigned* __restrict__ minM,
    const float* __restrict__ x2, const float* __restrict__ y2,
    unsigned* __restrict__ gmax) {
  int dir = blockIdx.x >> 5;
  int blk = blockIdx.x & 31;
  const unsigned* src = dir ? minM : minN;
  const float* nrm = dir ? y2 : x2;
  size_t base = (size_t)blk * 256;  // in uint4/float4 units
  float mx = -INFINITY;
  for (int i = threadIdx.x; i < 256; i += 256) {
    uint4 k = ((const uint4*)src)[base + i];
    float4 nv = ((const float4*)nrm)[base + i];
    mx = fmaxf(mx, nv.x + funkey(k.x));
    mx = fmaxf(mx, nv.y + funkey(k.y));
    mx = fmaxf(mx, nv.z + funkey(k.z));
    mx = fmaxf(mx, nv.w + funkey(k.w));
  }
#pragma unroll
  for (int mask = 1; mask < 64; mask <<= 1) mx = fmaxf(mx, __shfl_xor(mx, mask));
  __shared__ float sm[4];
  if ((threadIdx.x & 63) == 0) sm[threadIdx.x >> 6] = mx;
  __syncthreads();
  if (threadIdx.x == 0) {
    mx = fmaxf(fmaxf(sm[0], sm[1]), fmaxf(sm[2], sm[3]));
    atomicMax(&gmax[dir], fkey(mx));
  }
}

__global__ void final2_kernel(const unsigned* __restrict__ gmax, float* __restrict__ out) {
  if (threadIdx.x == 0)
    out[0] = sqrtf(fmaxf(funkey(gmax[0]), 1e-12f)) +
             sqrtf(fmaxf(funkey(gmax[1]), 1e-12f));
}

extern "C" void kernel_launch(void* const* d_in, const int* in_sizes, int n_in,
                              void* d_out, int out_size, void* d_ws, size_t ws_size,
                              hipStream_t stream) {
  const float* pred = (const float*)d_in[0];
  const float* label = (const float*)d_in[1];
  char* ws = (char*)d_ws;

  const size_t bfBytes = (size_t)BNT * D_ * 2;  // 4 MB per array
  const size_t needFast = 2 * bfBytes + (size_t)(BNT + BMT) * 8 + 64;

  if (ws_size >= needFast) {
    unsigned short* predbf = (unsigned short*)ws;
    unsigned short* labelbf = (unsigned short*)(ws + bfBytes);
    float* x2 = (float*)(ws + 2 * bfBytes);
    float* y2 = x2 + BNT;
    unsigned* minN = (unsigned*)(y2 + BMT);
    unsigned* minM = minN + BNT;
    unsigned* gmax = minM + BMT;

    prep_kernel<true><<<(BNT + BMT) / 16, 256, 0, stream>>>(
        pred, label, predbf, labelbf, x2, y2, minN, minM, gmax);
    fused_kernel<true><<<dim3(N_ / TA, MCHUNK, B_), 256, 0, stream>>>(
        predbf, labelbf, x2, y2, minN, minM);
    final1_kernel<<<64, 256, 0, stream>>>(minN, minM, x2, y2, gmax);
    final2_kernel<<<1, 64, 0, stream>>>(gmax, (float*)d_out);
  } else {
    float* x2 = (float*)ws;
    float* y2 = x2 + BNT;
    unsigned* minN = (unsigned*)(y2 + BMT);
    unsigned* minM = minN + BNT;
    unsigned* gmax = minM + BMT;

    prep_kernel<false><<<(BNT + BMT) / 16, 256, 0, stream>>>(
        pred, label, nullptr, nullptr, x2, y2, minN, minM, gmax);
    fused_kernel<false><<<dim3(N_ / TA, MCHUNK, B_), 256, 0, stream>>>(
        pred, label, x2, y2, minN, minM);
    final1_kernel<<<64, 256, 0, stream>>>(minN, minM, x2, y2, gmax);
    final2_kernel<<<1, 64, 0, stream>>>(gmax, (float*)d_out);
  }
}

// Round 7
// 69.290 us; speedup vs baseline: 3.1161x; 3.1161x over previous
//
#include <hip/hip_runtime.h>
#include <hip/hip_bf16.h>

#define B_ 8
#define N_ 4096
#define M_ 4096
#define D_ 64
#define BNT (B_ * N_)   // 32768
#define BMT (B_ * M_)   // 32768
#define TA 128          // A band rows per block (fragments in registers)
#define TB 128          // B tile rows (LDS, double-buffered)
#define CHUNK_TILES 8   // B tiles per block
#define CHUNK_B (TB * CHUNK_TILES)        // 1024
#define MCHUNK (M_ / CHUNK_B)             // 4

typedef short bf16x8 __attribute__((ext_vector_type(8)));
typedef float f32x4 __attribute__((ext_vector_type(4)));

__device__ __forceinline__ unsigned short f2bf(float f) {
  __hip_bfloat16 h = __float2bfloat16(f);
  return *reinterpret_cast<unsigned short*>(&h);
}

// Order-preserving float -> uint key for atomicMin/atomicMax(unsigned).
__device__ __forceinline__ unsigned fkey(float f) {
  unsigned b = __float_as_uint(f);
  return b ^ ((unsigned)((int)b >> 31) | 0x80000000u);
}
__device__ __forceinline__ float funkey(unsigned k) {
  unsigned b = (k & 0x80000000u) ? (k ^ 0x80000000u) : ~k;
  return __uint_as_float(b);
}

__device__ __forceinline__ bf16x8 cvt8(float4 lo, float4 hi) {
  union { unsigned short u[8]; bf16x8 v; } r;
  r.u[0] = f2bf(lo.x); r.u[1] = f2bf(lo.y); r.u[2] = f2bf(lo.z); r.u[3] = f2bf(lo.w);
  r.u[4] = f2bf(hi.x); r.u[5] = f2bf(hi.y); r.u[6] = f2bf(hi.z); r.u[7] = f2bf(hi.w);
  return r.v;
}

__device__ __forceinline__ void gload_lds16(const void* g, void* l) {
  __builtin_amdgcn_global_load_lds(
      (const __attribute__((address_space(1))) unsigned int*)g,
      (__attribute__((address_space(3))) unsigned int*)l, 16, 0, 0);
}

// Stage a ROWSx64 bf16 tile into XOR-swizzled LDS (row pitch 128B,
// swizzle byte ^= (row&7)<<4). BF: direct global->LDS DMA with pre-swizzled
// per-lane source (m173). !BF: fp32 load + convert + swizzled ds_write.
template <int ROWS, bool BF>
__device__ __forceinline__ void stage_tile(const void* gsrc, unsigned short* lds,
                                           int t, int srcpat) {
  if (BF) {
    constexpr int PER_WAVE = (ROWS * 128 / 1024) / 4;
    const char* gp = (const char*)gsrc;
    int w = t >> 6;
#pragma unroll
    for (int i = 0; i < PER_WAVE; i++) {
      int q = w * PER_WAVE + i;
      gload_lds16(gp + q * 1024 + srcpat, (char*)lds + q * 1024);
    }
  } else {
    const float4* g4 = (const float4*)gsrc;
#pragma unroll
    for (int i = 0; i < ROWS * 16 / 256; i++) {
      int off = i * 256 + t;
      float4 v = g4[off];
      int row = off >> 4;
      int cb = (off & 15) * 8;
      int ba = (row * 128 + cb) ^ ((row & 7) << 4);
      ushort4 p;
      p.x = f2bf(v.x); p.y = f2bf(v.y); p.z = f2bf(v.z); p.w = f2bf(v.w);
      *(ushort4*)((char*)lds + ba) = p;
    }
  }
}

// Kernel 1: norms + min-array + gmax init (+ optional conversion).
// predbf gets -2*pred folded in (exact power-of-2 scale, no extra rounding):
// the fused gram then directly produces y2 - 2<a,b> via MFMA C-injection.
template <bool CONV>
__global__ __launch_bounds__(256) void prep_kernel(
    const float* __restrict__ pred, const float* __restrict__ label,
    unsigned short* __restrict__ predbf, unsigned short* __restrict__ labelbf,
    float* __restrict__ x2, float* __restrict__ y2,
    unsigned* __restrict__ minN, unsigned* __restrict__ minM,
    unsigned* __restrict__ gmax) {
  int t = threadIdx.x;
  int lane = t & 15;
  long row = (long)blockIdx.x * 16 + (t >> 4);
  bool isA = row < BNT;
  const float4* src;
  unsigned short* bdst;
  float* ndst;
  unsigned* mdst;
  if (isA) {
    src = (const float4*)(pred + row * D_);
    bdst = predbf + row * D_;
    ndst = x2 + row;
    mdst = minN + row;
  } else {
    long r2 = row - BNT;
    src = (const float4*)(label + r2 * D_);
    bdst = labelbf + r2 * D_;
    ndst = y2 + r2;
    mdst = minM + r2;
  }
  float4 v = src[lane];
  if (CONV) {
    float s = isA ? -2.f : 1.f;
    ushort4 p;
    p.x = f2bf(s * v.x); p.y = f2bf(s * v.y);
    p.z = f2bf(s * v.z); p.w = f2bf(s * v.w);
    *(ushort4*)(bdst + lane * 4) = p;
  }
  float s = v.x * v.x + v.y * v.y + v.z * v.z + v.w * v.w;
  s += __shfl_xor(s, 1);
  s += __shfl_xor(s, 2);
  s += __shfl_xor(s, 4);
  s += __shfl_xor(s, 8);
  if (lane == 0) {
    *ndst = s;
    *mdst = 0xFFFFFFFFu;  // +inf key
  }
  if (blockIdx.x == 0 && t < 2) gmax[t] = 0u;
}

// Kernel 2: fused big-tile pass. Block = 4 waves (2x2), A-band 128 rows in
// registers (wave row-half), B staged in double-buffered 128-row LDS tiles.
// Per iter: 128x128 output tile, 32 MFMA/wave. acc initialized to splat(y2[m])
// and A pre-scaled by -2  =>  acc = y2[m] - 2<a,b> straight out of MFMA.
// NOTE: no min-waves clamp — R5's __launch_bounds__(256,3) capped VGPRs and
// caused 374 MB of scratch-spill traffic (the R5 regression).
template <bool BF>
__global__ __launch_bounds__(256) void fused_kernel(
    const void* __restrict__ Asrc, const void* __restrict__ Bsrc,
    const float* __restrict__ x2g, const float* __restrict__ y2g,
    unsigned* __restrict__ minN, unsigned* __restrict__ minM) {
  __shared__ alignas(16) unsigned short Bs[2][TB * 64];
  __shared__ float y2l[CHUNK_B];
  __shared__ float cmSlab[2][CHUNK_B];
  __shared__ float red[2][TA];

  const int t = threadIdx.x;
  const int b = blockIdx.z;
  const int a0 = blockIdx.x * TA;
  const int m0 = blockIdx.y * CHUNK_B;
  const int w = t >> 6, l = t & 63;
  const int g = l >> 4, c = l & 15;
  const int wr = w >> 1, wc = w & 1;
  const int srcpat = (l >> 3) * 128 + (((l & 7) * 16) ^ ((l >> 3) << 4));

  const size_t rowbytes = BF ? 128 : 256;
  const char* Bgl = (const char*)Bsrc + ((size_t)b * M_ + m0) * rowbytes;

  // y2 chunk -> LDS (4KB, once)
  ((float4*)y2l)[t] = ((const float4*)(y2g + (size_t)b * M_ + m0))[t];

  // stage first B tile
  stage_tile<TB, BF>(Bgl, Bs[0], t, srcpat);

  // A fragments (this wave's 64-row half), direct global->reg
  bf16x8 af[2][4];
  if (BF) {
    const unsigned short* Ab =
        (const unsigned short*)Asrc + ((size_t)b * N_ + a0) * D_;
#pragma unroll
    for (int kk = 0; kk < 2; kk++)
#pragma unroll
      for (int mi = 0; mi < 4; mi++)
        af[kk][mi] =
            *(const bf16x8*)(Ab + (size_t)(wr * 64 + mi * 16 + c) * D_ + kk * 32 + g * 8);
  } else {
    const float* Af = (const float*)Asrc + ((size_t)b * N_ + a0) * D_;
#pragma unroll
    for (int kk = 0; kk < 2; kk++)
#pragma unroll
      for (int mi = 0; mi < 4; mi++) {
        const float4* p =
            (const float4*)(Af + (size_t)(wr * 64 + mi * 16 + c) * D_ + kk * 32 + g * 8);
        float4 lo = p[0], hi = p[1];
        lo.x *= -2.f; lo.y *= -2.f; lo.z *= -2.f; lo.w *= -2.f;
        hi.x *= -2.f; hi.y *= -2.f; hi.z *= -2.f; hi.w *= -2.f;
        af[kk][mi] = cvt8(lo, hi);
      }
  }

  // x2 per output A-row (loop-invariant)
  float x2v[4][4];
#pragma unroll
  for (int mi = 0; mi < 4; mi++)
#pragma unroll
    for (int e = 0; e < 4; e++)
      x2v[mi][e] = x2g[(size_t)b * N_ + a0 + wr * 64 + mi * 16 + g * 4 + e];

  float rmin[4][4];
#pragma unroll
  for (int mi = 0; mi < 4; mi++)
#pragma unroll
    for (int e = 0; e < 4; e++) rmin[mi][e] = INFINITY;

  __syncthreads();  // first tile + y2l ready

#pragma unroll
  for (int it = 0; it < CHUNK_TILES; it++) {
    if (it + 1 < CHUNK_TILES)
      stage_tile<TB, BF>(Bgl + (size_t)(it + 1) * TB * rowbytes,
                         Bs[(it + 1) & 1], t, srcpat);
    const char* Bcur = (const char*)Bs[it & 1];

    float nbv[4];
#pragma unroll
    for (int ni = 0; ni < 4; ni++)
      nbv[ni] = y2l[it * TB + wc * 64 + ni * 16 + c];

#pragma unroll
    for (int h = 0; h < 2; h++) {
      // B fragments for 2 ni columns (this wave's wc half)
      bf16x8 b0[2], b1[2];
#pragma unroll
      for (int nj = 0; nj < 2; nj++) {
        int r = wc * 64 + (h * 2 + nj) * 16 + c;
        b0[nj] = *(const bf16x8*)(Bcur + ((r * 128 + g * 16) ^ ((r & 7) << 4)));
        b1[nj] = *(const bf16x8*)(Bcur + ((r * 128 + 64 + g * 16) ^ ((r & 7) << 4)));
      }
      // acc init = splat(y2[m]); A carries -2 => acc = y2 - 2<a,b>
      f32x4 acc[4][2];
#pragma unroll
      for (int mi = 0; mi < 4; mi++)
#pragma unroll
        for (int nj = 0; nj < 2; nj++) {
          float nv = nbv[h * 2 + nj];
          acc[mi][nj] = (f32x4){nv, nv, nv, nv};
        }
#pragma unroll
      for (int mi = 0; mi < 4; mi++)
#pragma unroll
        for (int nj = 0; nj < 2; nj++)
          acc[mi][nj] = __builtin_amdgcn_mfma_f32_16x16x32_bf16(
              af[0][mi], b0[nj], acc[mi][nj], 0, 0, 0);
#pragma unroll
      for (int mi = 0; mi < 4; mi++)
#pragma unroll
        for (int nj = 0; nj < 2; nj++)
          acc[mi][nj] = __builtin_amdgcn_mfma_f32_16x16x32_bf16(
              af[1][mi], b1[nj], acc[mi][nj], 0, 0, 0);

      // epilogue: rmin = fmin(rmin, acc); cmin = min(acc + x2) - y2
#pragma unroll
      for (int nj = 0; nj < 2; nj++) {
        float cm = INFINITY;
#pragma unroll
        for (int mi = 0; mi < 4; mi++)
#pragma unroll
          for (int e = 0; e < 4; e++) {
            float v = acc[mi][nj][e];
            rmin[mi][e] = fminf(rmin[mi][e], v);
            cm = fminf(cm, v + x2v[mi][e]);
          }
        cm = fminf(cm, __shfl_xor(cm, 16));
        cm = fminf(cm, __shfl_xor(cm, 32));
        if (g == 0)
          cmSlab[wr][it * TB + wc * 64 + (h * 2 + nj) * 16 + c] =
              cm - nbv[h * 2 + nj];
      }
    }
    __syncthreads();
  }

  // rmin finish: c-lane shfl reduce, cross-wc LDS combine, one atomic per row
#pragma unroll
  for (int mi = 0; mi < 4; mi++)
#pragma unroll
    for (int e = 0; e < 4; e++) {
      float r = rmin[mi][e];
      r = fminf(r, __shfl_xor(r, 1));
      r = fminf(r, __shfl_xor(r, 2));
      r = fminf(r, __shfl_xor(r, 4));
      r = fminf(r, __shfl_xor(r, 8));
      rmin[mi][e] = r;
    }
  if (c == 0) {
#pragma unroll
    for (int mi = 0; mi < 4; mi++)
#pragma unroll
      for (int e = 0; e < 4; e++)
        red[wc][wr * 64 + mi * 16 + g * 4 + e] = rmin[mi][e];
  }
  __syncthreads();
  if (t < TA) {
    float m = fminf(red[0][t], red[1][t]);
    atomicMin(&minN[(size_t)b * N_ + a0 + t], fkey(m));
  }
  // col-min flush: combine wr slabs, one atomic per B row of the chunk
#pragma unroll
  for (int i = 0; i < CHUNK_B / 256; i++) {
    int r = i * 256 + t;
    float v = fminf(cmSlab[0][r], cmSlab[1][r]);
    atomicMin(&minM[(size_t)b * M_ + m0 + r], fkey(v));
  }
}

// Kernel 3a: per-slice max of (norm + min), atomicMax into gmax[dir].
__global__ __launch_bounds__(256) void final1_kernel(
    const unsigned* __restrict__ minN, const unsigned* __restrict__ minM,
    const float* __restrict__ x2, const float* __restrict__ y2,
    unsigned* __restrict__ gmax) {
  int dir = blockIdx.x >> 5;
  int blk = blockIdx.x & 31;
  const unsigned* src = dir ? minM : minN;
  const float* nrm = dir ? y2 : x2;
  size_t base = (size_t)blk * 256;  // in uint4/float4 units
  float mx = -INFINITY;
  {
    int i = threadIdx.x;
    uint4 k = ((const uint4*)src)[base + i];
    float4 nv = ((const float4*)nrm)[base + i];
    mx = fmaxf(mx, nv.x + funkey(k.x));
    mx = fmaxf(mx, nv.y + funkey(k.y));
    mx = fmaxf(mx, nv.z + funkey(k.z));
    mx = fmaxf(mx, nv.w + funkey(k.w));
  }
#pragma unroll
  for (int mask = 1; mask < 64; mask <<= 1) mx = fmaxf(mx, __shfl_xor(mx, mask));
  __shared__ float sm[4];
  if ((threadIdx.x & 63) == 0) sm[threadIdx.x >> 6] = mx;
  __syncthreads();
  if (threadIdx.x == 0) {
    mx = fmaxf(fmaxf(sm[0], sm[1]), fmaxf(sm[2], sm[3]));
    atomicMax(&gmax[dir], fkey(mx));
  }
}

__global__ void final2_kernel(const unsigned* __restrict__ gmax, float* __restrict__ out) {
  if (threadIdx.x == 0)
    out[0] = sqrtf(fmaxf(funkey(gmax[0]), 1e-12f)) +
             sqrtf(fmaxf(funkey(gmax[1]), 1e-12f));
}

extern "C" void kernel_launch(void* const* d_in, const int* in_sizes, int n_in,
                              void* d_out, int out_size, void* d_ws, size_t ws_size,
                              hipStream_t stream) {
  const float* pred = (const float*)d_in[0];
  const float* label = (const float*)d_in[1];
  char* ws = (char*)d_ws;

  const size_t bfBytes = (size_t)BNT * D_ * 2;  // 4 MB per array
  const size_t needFast = 2 * bfBytes + (size_t)(BNT + BMT) * 8 + 64;

  if (ws_size >= needFast) {
    unsigned short* predbf = (unsigned short*)ws;
    unsigned short* labelbf = (unsigned short*)(ws + bfBytes);
    float* x2 = (float*)(ws + 2 * bfBytes);
    float* y2 = x2 + BNT;
    unsigned* minN = (unsigned*)(y2 + BMT);
    unsigned* minM = minN + BNT;
    unsigned* gmax = minM + BMT;

    prep_kernel<true><<<(BNT + BMT) / 16, 256, 0, stream>>>(
        pred, label, predbf, labelbf, x2, y2, minN, minM, gmax);
    fused_kernel<true><<<dim3(N_ / TA, MCHUNK, B_), 256, 0, stream>>>(
        predbf, labelbf, x2, y2, minN, minM);
    final1_kernel<<<64, 256, 0, stream>>>(minN, minM, x2, y2, gmax);
    final2_kernel<<<1, 64, 0, stream>>>(gmax, (float*)d_out);
  } else {
    float* x2 = (float*)ws;
    float* y2 = x2 + BNT;
    unsigned* minN = (unsigned*)(y2 + BMT);
    unsigned* minM = minN + BNT;
    unsigned* gmax = minM + BMT;

    prep_kernel<false><<<(BNT + BMT) / 16, 256, 0, stream>>>(
        pred, label, nullptr, nullptr, x2, y2, minN, minM, gmax);
    fused_kernel<false><<<dim3(N_ / TA, MCHUNK, B_), 256, 0, stream>>>(
        pred, label, x2, y2, minN, minM);
    final1_kernel<<<64, 256, 0, stream>>>(minN, minM, x2, y2, gmax);
    final2_kernel<<<1, 64, 0, stream>>>(gmax, (float*)d_out);
  }
}